// Round 1
// baseline (518.303 us; speedup 1.0000x reference)
//
#include <hip/hip_runtime.h>
#include <hip/hip_bf16.h>

// MultiheadBlockAttention: B=4, S=512, NB=32, D=512, H=8, dh=64.
// Fully fused: one workgroup per (b,s). Projections (M=32,N=512,K=512, x3)
// via v_mfma_f32_32x32x16_bf16 with X staged in swizzled LDS and bf16
// weights streamed from L2 (pre-converted into d_ws by wconv_kernel).
// Q/K/V live only in LDS; attention done per-head (wave h = head h).
// Outputs: d_out = [attn_output (B,S,NB,D) f32 | attn_weight (B,H,S,NB,NB) f32].

#define NBD (32 * 512)  // elements per (b,s) slice

typedef __bf16 bf16x8 __attribute__((ext_vector_type(8)));
typedef float f32x16 __attribute__((ext_vector_type(16)));

// f32 -> bf16 bits, round-to-nearest-even. Result in low 16 bits.
__device__ __forceinline__ unsigned f2b(float f) {
  union { float f; unsigned u; } v;
  v.f = f;
  return (v.u + 0x7fffu + ((v.u >> 16) & 1u)) >> 16;
}

__device__ __forceinline__ f32x16 mfma32(uint4 a, uint4 b, f32x16 c) {
  union { uint4 u; bf16x8 v; } ua, ub;
  ua.u = a;
  ub.u = b;
  return __builtin_amdgcn_mfma_f32_32x32x16_bf16(ua.v, ub.v, c, 0, 0, 0);
}

// Convert wq|wk|wv (each 512x512 f32) to bf16 into ws. 65536 float4 per matrix.
__global__ void wconv_kernel(const float* __restrict__ wq,
                             const float* __restrict__ wk,
                             const float* __restrict__ wv,
                             unsigned short* __restrict__ out) {
  const int i = blockIdx.x * blockDim.x + threadIdx.x;  // 0..65535
  const float* src[3] = {wq, wk, wv};
#pragma unroll
  for (int m = 0; m < 3; ++m) {
    float4 f = ((const float4*)src[m])[i];
    ushort4 o;
    o.x = (unsigned short)f2b(f.x);
    o.y = (unsigned short)f2b(f.y);
    o.z = (unsigned short)f2b(f.z);
    o.w = (unsigned short)f2b(f.w);
    ((ushort4*)out)[m * 65536 + i] = o;
  }
}

__global__ __launch_bounds__(512, 2)
void mhba_kernel(const float* __restrict__ q_in, const float* __restrict__ k_in,
                 const float* __restrict__ v_in, const float* __restrict__ mask,
                 const float* __restrict__ bq, const float* __restrict__ bk,
                 const float* __restrict__ bv,
                 const unsigned short* __restrict__ wbf,  // [3][512][512] bf16
                 float* __restrict__ out_attn,            // [B,S,NB,D]
                 float* __restrict__ out_w) {             // [B,H,S,NB,NB]
  // Row-major [32][512] bf16 tiles, byte addr swizzled with ((row&7)<<4)
  // to break the 1024B-row-stride bank conflict on ds_read_b128.
  __shared__ unsigned short Xs[NBD];
  __shared__ unsigned short Qs[NBD];
  __shared__ unsigned short Ks[NBD];
  __shared__ unsigned short Vs[NBD];
  __shared__ unsigned short AW[8][1024];  // per-wave P (32x32 bf16), ((n&3)<<4) swizzle

  const int bs = blockIdx.x;     // (b,s): b = bs>>9, s = bs&511
  const int tid = threadIdx.x;   // 0..511
  const int lane = tid & 63;
  const int wave = tid >> 6;     // 0..7
  const int l31 = lane & 31;
  const int half = lane >> 5;

  const float* srcG[3] = {q_in, k_in, v_in};
  const float* biasG[3] = {bq, bk, bv};
  unsigned short* dstL[3] = {Qs, Ks, Vs};

  // ---------------- projections: Q/K/V = X @ W^T + b ----------------
#pragma unroll
  for (int m = 0; m < 3; ++m) {
    __syncthreads();  // protect Xs from previous iteration's readers
    // Stage X: 16384 f32 -> bf16 LDS, coalesced float4 loads.
    const float4* src4 = (const float4*)(srcG[m] + (size_t)bs * NBD);
#pragma unroll
    for (int i = 0; i < 8; ++i) {
      const int idx4 = i * 512 + tid;   // 0..4095, 128 float4 per row
      float4 f = src4[idx4];
      const int n = idx4 >> 7;
      const int k4 = idx4 & 127;
      uint2 u;
      u.x = f2b(f.x) | (f2b(f.y) << 16);
      u.y = f2b(f.z) | (f2b(f.w) << 16);
      const unsigned off = (unsigned)(n * 1024 + k4 * 8) ^ ((unsigned)(n & 7) << 4);
      *(uint2*)((char*)Xs + off) = u;
    }
    __syncthreads();

    const unsigned short* wmat = wbf + (size_t)m * (512 * 512);
#pragma unroll
    for (int t = 0; t < 2; ++t) {
      const int ntile = wave * 2 + t;        // 16 N-tiles of 32 cols
      const int col = ntile * 32 + l31;      // output col == weight row j
      const uint4* wrow = (const uint4*)(wmat + (size_t)col * 512);
      const unsigned abase = (unsigned)(l31 * 1024 + half * 16);
      const unsigned aswz = (unsigned)(l31 & 7) << 4;
      f32x16 acc0, acc1;
#pragma unroll
      for (int r = 0; r < 16; ++r) { acc0[r] = 0.0f; acc1[r] = 0.0f; }
      // K=512 -> 32 MFMAs; two accumulators to break the dependent chain.
#pragma unroll 4
      for (int i = 0; i < 16; ++i) {
        const int kk0 = 2 * i, kk1 = 2 * i + 1;
        uint4 a0 = *(const uint4*)((const char*)Xs + ((abase + kk0 * 32) ^ aswz));
        uint4 b0 = wrow[kk0 * 2 + half];
        uint4 a1 = *(const uint4*)((const char*)Xs + ((abase + kk1 * 32) ^ aswz));
        uint4 b1 = wrow[kk1 * 2 + half];
        acc0 = mfma32(a0, b0, acc0);
        acc1 = mfma32(a1, b1, acc1);
      }
      const float bias = biasG[m][col];
      unsigned short* dst = dstL[m];
      // C/D layout: col = l31 (fixed per lane), row n per reg.
#pragma unroll
      for (int r = 0; r < 16; ++r) {
        const int n = (r & 3) + 8 * (r >> 2) + 4 * half;
        const unsigned off = (unsigned)(n * 1024 + col * 2) ^ ((unsigned)(n & 7) << 4);
        *(unsigned short*)((char*)dst + off) = (unsigned short)f2b(acc0[r] + acc1[r] + bias);
      }
    }
  }
  __syncthreads();

  // ---------------- attention: wave == head ----------------
  const int h = wave;
  const int b = bs >> 9;
  const int s = bs & 511;

  // logits = Qh @ Kh^T : A-frag from Q row l31, B-frag from K row l31 (same addressing)
  f32x16 lg;
#pragma unroll
  for (int r = 0; r < 16; ++r) lg[r] = 0.0f;
  const unsigned qbase = (unsigned)(l31 * 1024 + h * 128 + half * 16);
  const unsigned qswz = (unsigned)(l31 & 7) << 4;
#pragma unroll
  for (int kk = 0; kk < 4; ++kk) {
    uint4 aq = *(const uint4*)((const char*)Qs + ((qbase + kk * 32) ^ qswz));
    uint4 bkf = *(const uint4*)((const char*)Ks + ((qbase + kk * 32) ^ qswz));
    lg = mfma32(aq, bkf, lg);
  }

  // scale 1/sqrt(64), additive mask over m (= l31), row softmax across the
  // 32 lanes of each half (C/D layout holds a full row per reg per half).
  const float mk = mask[bs * 32 + l31];
  float w16[16];
#pragma unroll
  for (int r = 0; r < 16; ++r) {
    const float x = lg[r] * 0.125f + mk;
    float mx = x;
#pragma unroll
    for (int d = 16; d >= 1; d >>= 1) mx = fmaxf(mx, __shfl_xor(mx, d));
    const float e = __expf(x - mx);
    float ss = e;
#pragma unroll
    for (int d = 16; d >= 1; d >>= 1) ss += __shfl_xor(ss, d);
    w16[r] = e / ss;
  }

  // write attn_weight + stash bf16 P in per-wave LDS for PV A-frags
  float* wout = out_w + ((size_t)((b * 8 + h) * 512 + s)) * 1024;
  unsigned short* aw = &AW[h][0];
#pragma unroll
  for (int r = 0; r < 16; ++r) {
    const int n = (r & 3) + 8 * (r >> 2) + 4 * half;
    wout[n * 32 + l31] = w16[r];
    const unsigned off = (unsigned)(n * 64 + l31 * 2) ^ ((unsigned)(n & 3) << 4);
    *(unsigned short*)((char*)aw + off) = (unsigned short)f2b(w16[r]);
  }
  // same-wave LDS write->read: HW processes DS ops in order per wave.

  // O = P @ Vh : two 32-col tiles over dh=64, K=32 (kk=0,1)
  f32x16 o0, o1;
#pragma unroll
  for (int r = 0; r < 16; ++r) { o0[r] = 0.0f; o1[r] = 0.0f; }
  const unsigned vcol = (unsigned)((h * 64 + l31) * 2);
#pragma unroll
  for (int kk = 0; kk < 2; ++kk) {
    const unsigned aoff =
        (unsigned)(l31 * 64 + kk * 32 + half * 16) ^ ((unsigned)(l31 & 3) << 4);
    uint4 af = *(const uint4*)((const char*)aw + aoff);
    // B-frag: lane holds V[m = kk*16+half*8+j][h*64 + tile*32 + l31]; 8 rows ->
    // 8 scalar u16 reads per tile (contiguous across lanes, conflict-free).
    unsigned pk0[4] = {0, 0, 0, 0}, pk1[4] = {0, 0, 0, 0};
#pragma unroll
    for (int j = 0; j < 8; ++j) {
      const int mrow = kk * 16 + half * 8 + j;
      const unsigned rb = (unsigned)(mrow * 1024);
      const unsigned sw = (unsigned)(mrow & 7) << 4;
      const unsigned v0 = *(const unsigned short*)((const char*)Vs + ((rb + vcol) ^ sw));
      const unsigned v1 = *(const unsigned short*)((const char*)Vs + ((rb + vcol + 64) ^ sw));
      pk0[j >> 1] |= v0 << ((j & 1) * 16);
      pk1[j >> 1] |= v1 << ((j & 1) * 16);
    }
    uint4 b0, b1;
    b0.x = pk0[0]; b0.y = pk0[1]; b0.z = pk0[2]; b0.w = pk0[3];
    b1.x = pk1[0]; b1.y = pk1[1]; b1.z = pk1[2]; b1.w = pk1[3];
    o0 = mfma32(af, b0, o0);
    o1 = mfma32(af, b1, o1);
  }

  float* obase = out_attn + (size_t)bs * NBD;
  const int ocol = h * 64 + l31;
#pragma unroll
  for (int r = 0; r < 16; ++r) {
    const int n = (r & 3) + 8 * (r >> 2) + 4 * half;
    obase[n * 512 + ocol] = o0[r];
    obase[n * 512 + ocol + 32] = o1[r];
  }
}

extern "C" void kernel_launch(void* const* d_in, const int* in_sizes, int n_in,
                              void* d_out, int out_size, void* d_ws, size_t ws_size,
                              hipStream_t stream) {
  const float* q    = (const float*)d_in[0];
  const float* k    = (const float*)d_in[1];
  const float* v    = (const float*)d_in[2];
  const float* mask = (const float*)d_in[3];
  const float* wq   = (const float*)d_in[4];
  const float* bq   = (const float*)d_in[5];
  const float* wk   = (const float*)d_in[6];
  const float* bk   = (const float*)d_in[7];
  const float* wv   = (const float*)d_in[8];
  const float* bv   = (const float*)d_in[9];

  unsigned short* wbf = (unsigned short*)d_ws;  // 3*512*512 bf16 = 1.5 MB
  float* out_attn = (float*)d_out;
  float* out_w = out_attn + (size_t)4 * 512 * 32 * 512;

  wconv_kernel<<<256, 256, 0, stream>>>(wq, wk, wv, wbf);
  mhba_kernel<<<2048, 512, 0, stream>>>(q, k, v, mask, bq, bk, bv, wbf,
                                        out_attn, out_w);
}